// Round 9
// baseline (496.029 us; speedup 1.0000x reference)
//
#include <hip/hip_runtime.h>
#include <hip/hip_bf16.h>

typedef _Float16 half8 __attribute__((ext_vector_type(8)));
typedef _Float16 half4v __attribute__((ext_vector_type(4)));
typedef float floatx4 __attribute__((ext_vector_type(4)));

#define N_EDGES 800000
#define N_NODES 50000
#define NPB 32            // fallback: nodes per gather block (local-bit packing)
#define NPB2 16           // gather2: nodes per block (128 threads)
#define NB_SCAN 196       // ceil(N_NODES / 256)
#define ACC_STRIDE 129    // fused-fallback accumulator stride
#define H1S 72            // halves: 144B row stride
#define H2S 40            // halves: 80B row stride
#define WSTR 68           // fused fallback: floats, 272B row stride
#define WH 136            // mlp kernel: halves, 272B row stride

#define S2   0.7071067811865475f
#define S2_3 0.4082482904638631f
#define INV_SQRT_MUL 0.17677669529663687f

__device__ __forceinline__ float silu_f(float x) {
    return x / (1.0f + __expf(-x));
}

// per-edge message accumulate (16 components owned by this thread: j-th 4 of out0 + 12 of out1)
__device__ __forceinline__ void msg_accum(const float4 ef,
                                          const half4v w0, const half4v w1,
                                          const half4v w2, const half4v w3,
                                          const float4 x0v, const float4 xa,
                                          const float4 xb, const float4 xc,
                                          float* __restrict__ acc0,
                                          float* __restrict__ accm)
{
    const float e0 = ef.x, e1x = ef.y, e1y = ef.z, e1z = ef.w;
    const float x0[4]  = {x0v.x, x0v.y, x0v.z, x0v.w};
    const float xx[12] = {xa.x, xa.y, xa.z, xa.w,
                          xb.x, xb.y, xb.z, xb.w,
                          xc.x, xc.y, xc.z, xc.w};
    #pragma unroll
    for (int k = 0; k < 4; ++k) {
        const float x1x = xx[3 * k], x1y = xx[3 * k + 1], x1z = xx[3 * k + 2];
        const float dot = x1x * e1x + x1y * e1y + x1z * e1z;
        acc0[k] += S2 * (float)w0[k] * x0[k] * e0 + S2_3 * (float)w3[k] * dot;
        const float a = S2 * (float)w1[k] * x0[k];
        const float b = S2 * (float)w2[k] * e0;
        accm[3 * k + 0] += a * e1x + b * x1x;
        accm[3 * k + 1] += a * e1y + b * x1y;
        accm[3 * k + 2] += a * e1z + b * x1z;
    }
}

// ---------------- CSR build: histogram (int4-vectorized) ----------------
__global__ __launch_bounds__(256)
void hist_kernel(const int* __restrict__ ei, int* __restrict__ counts)
{
    const int e4 = (blockIdx.x * 256 + threadIdx.x) * 4;
    if (e4 < N_EDGES) {   // N_EDGES % 4 == 0
        const int4 d = *(const int4*)(ei + N_EDGES + e4);
        atomicAdd(&counts[d.x], 1);
        atomicAdd(&counts[d.y], 1);
        atomicAdd(&counts[d.z], 1);
        atomicAdd(&counts[d.w], 1);
    }
}

// ---------------- CSR build: stage 1 — per-block scan + block sums ----------------
__global__ __launch_bounds__(256)
void bsum_kernel(const int* __restrict__ counts,
                 int* __restrict__ cursor,
                 int* __restrict__ bsum)
{
    __shared__ int buf[256];
    const int t = threadIdx.x;
    const int i = blockIdx.x * 256 + t;
    const int c = (i < N_NODES) ? counts[i] : 0;
    buf[t] = c;
    __syncthreads();
    #pragma unroll
    for (int off = 1; off < 256; off <<= 1) {
        const int x = (t >= off) ? buf[t - off] : 0;
        __syncthreads();
        buf[t] += x;
        __syncthreads();
    }
    if (i < N_NODES) cursor[i] = buf[t] - c;
    if (t == 255) bsum[blockIdx.x] = buf[255];
}

// ---------------- CSR build: stage 2 — scan block sums (block 0) + weight prep (block 1) ----------------
__global__ __launch_bounds__(256)
void scan_sums_kernel(const int* __restrict__ bsum,
                      int* __restrict__ boff,
                      int* __restrict__ row_ptr,
                      const float* __restrict__ W1,
                      const float* __restrict__ W2,
                      const float* __restrict__ W3,
                      _Float16* __restrict__ frags)
{
    const int t = threadIdx.x;
    if (blockIdx.x == 0) {
        __shared__ int buf[256];
        const int v = (t < NB_SCAN) ? bsum[t] : 0;
        buf[t] = v;
        __syncthreads();
        #pragma unroll
        for (int off = 1; off < 256; off <<= 1) {
            const int x = (t >= off) ? buf[t - off] : 0;
            __syncthreads();
            buf[t] += x;
            __syncthreads();
        }
        if (t < NB_SCAN) boff[t] = buf[t] - v;
        if (t == 0) row_ptr[N_NODES] = N_EDGES;
    } else {
        for (int idx = t; idx < 2048; idx += 256) {            // W1: 4 tiles
            const int j = idx & 7, l = (idx >> 3) & 63, tt = idx >> 9;
            frags[idx] = (_Float16)W1[((l >> 4) * 8 + j) * 64 + tt * 16 + (l & 15)];
        }
        for (int idx = t; idx < 2048; idx += 256) {            // W2: 2 k-chunks x 2 tiles
            const int j = idx & 7, l = (idx >> 3) & 63, tt = (idx >> 9) & 1, kc = idx >> 10;
            frags[2048 + idx] = (_Float16)W2[(kc * 32 + (l >> 4) * 8 + j) * 32 + tt * 16 + (l & 15)];
        }
        for (int idx = t; idx < 4096; idx += 256) {            // W3: 8 tiles
            const int j = idx & 7, l = (idx >> 3) & 63, tt = idx >> 9;
            frags[4096 + idx] = (_Float16)W3[((l >> 4) * 8 + j) * 128 + tt * 16 + (l & 15)];
        }
    }
}

// ---------------- CSR build: stage 3 — apply block offsets ----------------
__global__ __launch_bounds__(256)
void apply_kernel(const int* __restrict__ boff,
                  int* __restrict__ cursor,
                  int* __restrict__ row_ptr)
{
    const int i = blockIdx.x * 256 + threadIdx.x;
    if (i < N_NODES) {
        const int v = cursor[i] + boff[blockIdx.x];
        row_ptr[i] = v;
        cursor[i]  = v;
    }
}

// ---------------- CSR build: scatter (packs edge id + local, and src) ----------------
__global__ __launch_bounds__(256)
void scatter_kernel(const int* __restrict__ ei,
                    int* __restrict__ cursor,
                    int2* __restrict__ csr2)
{
    const int e = blockIdx.x * 256 + threadIdx.x;
    if (e < N_EDGES) {
        const int src = ei[e];
        const int dst = ei[N_EDGES + e];
        const int pos = atomicAdd(&cursor[dst], 1);
        csr2[pos] = make_int2(e | ((dst & (NPB - 1)) << 20), src);
    }
}

// ---------------- self-connection kernel (fallback path only) ----------------
__global__ __launch_bounds__(256)
void sc_kernel(const float* __restrict__ node_feat,
               const float* __restrict__ sc_w0,
               const float* __restrict__ sc_w1,
               float* __restrict__ out)
{
    __shared__ float sw0[1024];
    __shared__ float sw1[1024];
    __shared__ float xrow[256];

    const int t = threadIdx.x;
    ((float4*)sw0)[t] = ((const float4*)sc_w0)[t];
    ((float4*)sw1)[t] = ((const float4*)sc_w1)[t];
    __syncthreads();

    const int half = t >> 7;
    const int c    = t & 127;

    for (int it = 0; it < 4; ++it) {
        const int n = blockIdx.x * 8 + it * 2 + half;
        if (it) __syncthreads();
        xrow[t] = node_feat[(size_t)n * 128 + c];
        __syncthreads();
        const float* xr = xrow + half * 128;

        float acc = 0.0f;
        if (c < 32) {
            const int v = c;
            #pragma unroll
            for (int u = 0; u < 32; ++u) acc += xr[u] * sw0[u * 32 + v];
        } else {
            const int i = c - 32;
            const int v = i / 3;
            const int j = i - 3 * v;
            #pragma unroll
            for (int u = 0; u < 32; ++u) acc += xr[32 + u * 3 + j] * sw1[u * 32 + v];
        }
        out[(size_t)n * 128 + c] = acc * INV_SQRT_MUL;
    }
}

// ---------------- mlp kernel: CSR-ordered batch MLP, H1 double-buffered ----------------
// grid 3125 blocks x 4 waves x 4 tiles x 16 csr-slots = 800000
__global__ __launch_bounds__(256, 4)
void mlp_kernel(const int2* __restrict__ csr2,
                const float* __restrict__ edge_embed,
                const _Float16* __restrict__ frags,
                const float* __restrict__ B1,
                const float* __restrict__ B2,
                const float* __restrict__ B3,
                _Float16* __restrict__ w16)
{
    __shared__ _Float16 H1b[4][2][16 * H1S];   // double-buffered (tile parity)
    __shared__ _Float16 H2b[4][16 * H2S];
    __shared__ _Float16 Wf[4][16 * WH];

    const int t  = threadIdx.x;
    const int w  = t >> 6;
    const int l  = t & 63;
    const int lg = l >> 4;
    const int lr = l & 15;

    const half8* f8 = (const half8*)frags;
    half8 w1f[4], w2f[2][2], w3f[8];
    #pragma unroll
    for (int i = 0; i < 4; ++i) w1f[i] = f8[i * 64 + l];
    #pragma unroll
    for (int kc = 0; kc < 2; ++kc)
        #pragma unroll
        for (int i = 0; i < 2; ++i) w2f[kc][i] = f8[256 + kc * 128 + i * 64 + l];
    #pragma unroll
    for (int i = 0; i < 8; ++i) w3f[i] = f8[512 + i * 64 + l];

    float b1r[4], b2r[2], b3r[8];
    #pragma unroll
    for (int i = 0; i < 4; ++i) b1r[i] = B1[i * 16 + lr];
    #pragma unroll
    for (int i = 0; i < 2; ++i) b2r[i] = B2[i * 16 + lr];
    #pragma unroll
    for (int i = 0; i < 8; ++i) b3r[i] = B3[i * 16 + lr];

    const floatx4 zero = {0.f, 0.f, 0.f, 0.f};
    _Float16* h2p = H2b[w];
    _Float16* wp  = Wf[w];

    // ---- hoisted gathers: all 4 tiles' csr slots + embeddings up front ----
    const int slot0 = (blockIdx.x * 4 + w) * 64 + lr;
    int eArr[4];
    #pragma unroll
    for (int it = 0; it < 4; ++it) eArr[it] = csr2[slot0 + it * 16].x & 0xFFFFF;

    half8 a1f[4];
    #pragma unroll
    for (int it = 0; it < 4; ++it) {
        const float* ep = edge_embed + (size_t)eArr[it] * 32 + lg * 8;
        const float4 ea = *(const float4*)ep;
        const float4 eb = *(const float4*)(ep + 4);
        half8 a1;
        a1[0] = (_Float16)ea.x; a1[1] = (_Float16)ea.y;
        a1[2] = (_Float16)ea.z; a1[3] = (_Float16)ea.w;
        a1[4] = (_Float16)eb.x; a1[5] = (_Float16)eb.y;
        a1[6] = (_Float16)eb.z; a1[7] = (_Float16)eb.w;
        a1f[it] = a1;
    }

    #pragma unroll
    for (int it = 0; it < 4; ++it) {
        const int tb = (blockIdx.x * 4 + w) * 64 + it * 16;
        _Float16* h1p = H1b[w][it & 1];

        // ---- layer 1 ----
        #pragma unroll
        for (int tt = 0; tt < 4; ++tt) {
            floatx4 c = __builtin_amdgcn_mfma_f32_16x16x32_f16(a1f[it], w1f[tt], zero, 0, 0, 0);
            #pragma unroll
            for (int r = 0; r < 4; ++r) {
                const float v = silu_f(c[r] + b1r[tt]);
                h1p[(lg * 4 + r) * H1S + tt * 16 + lr] = (_Float16)v;
            }
        }
        const half8 a2_0 = *(const half8*)&h1p[lr * H1S +      lg * 8];
        const half8 a2_1 = *(const half8*)&h1p[lr * H1S + 32 + lg * 8];

        // ---- layer 2 ----
        #pragma unroll
        for (int tt = 0; tt < 2; ++tt) {
            floatx4 c = __builtin_amdgcn_mfma_f32_16x16x32_f16(a2_0, w2f[0][tt], zero, 0, 0, 0);
            c = __builtin_amdgcn_mfma_f32_16x16x32_f16(a2_1, w2f[1][tt], c, 0, 0, 0);
            #pragma unroll
            for (int r = 0; r < 4; ++r) {
                const float v = silu_f(c[r] + b2r[tt]);
                h2p[(lg * 4 + r) * H2S + tt * 16 + lr] = (_Float16)v;
            }
        }
        const half8 a3 = *(const half8*)&h2p[lr * H2S + lg * 8];

        // ---- layer 3: all 8 tiles -> Wf (f16, bias added) ----
        #pragma unroll
        for (int tt = 0; tt < 8; ++tt) {
            floatx4 c = __builtin_amdgcn_mfma_f32_16x16x32_f16(a3, w3f[tt], zero, 0, 0, 0);
            #pragma unroll
            for (int r = 0; r < 4; ++r)
                wp[(lg * 4 + r) * WH + tt * 16 + lr] = (_Float16)(c[r] + b3r[tt]);
        }

        // ---- readback + coalesced f16 store at CSR position tb+row (sequential) ----
        {
            const int row = l >> 2;
            const int m   = l & 3;
            const _Float16* src = wp + row * WH + m * 32;
            _Float16* dst = w16 + (size_t)(tb + row) * 128 + m * 32;
            #pragma unroll
            for (int c4 = 0; c4 < 4; ++c4)
                *(half8*)(dst + c4 * 8) = *(const half8*)(src + c4 * 8);
        }
    }
}

// ---------------- gather2: 8 threads/node, EPT=2, register accumulation + fused self-connection ----------------
// block 128 = 16 nodes x 8 threads; grid 3125 (covers 50000 exactly)
__global__ __launch_bounds__(128, 4)
void gather2_kernel(const int2* __restrict__ csr2,
                    const int* __restrict__ row_ptr,
                    const float* __restrict__ node_feat,
                    const float* __restrict__ edge_feat,
                    const _Float16* __restrict__ w16,
                    const float* __restrict__ sc_w0,
                    const float* __restrict__ sc_w1,
                    float* __restrict__ out)
{
    __shared__ float sw0[1024];
    __shared__ float sw1[1024];
    __shared__ float xown[NPB2 * 129];

    const int t     = threadIdx.x;
    const int local = t >> 3;
    const int j     = t & 7;
    const int n     = blockIdx.x * NPB2 + local;   // always < N_NODES

    #pragma unroll
    for (int r = 0; r < 2; ++r) {
        ((float4*)sw0)[t + 128 * r] = ((const float4*)sc_w0)[t + 128 * r];
        ((float4*)sw1)[t + 128 * r] = ((const float4*)sc_w1)[t + 128 * r];
    }
    {
        const float4* nr = (const float4*)(node_feat + (size_t)n * 128);
        float* xw = xown + local * 129;
        #pragma unroll
        for (int k = 0; k < 4; ++k) {
            const float4 v = nr[j + 8 * k];
            const int o = 4 * (j + 8 * k);
            xw[o] = v.x; xw[o + 1] = v.y; xw[o + 2] = v.z; xw[o + 3] = v.w;
        }
    }
    __syncthreads();

    const int beg = row_ptr[n];
    const int end = row_ptr[n + 1];

    float acc0[4]  = {0.f, 0.f, 0.f, 0.f};
    float accm[12] = {0.f};

    int i = beg;
    if ((end - beg) & 1) {
        const int2 c2 = csr2[i];
        const int e   = c2.x & 0xFFFFF;
        const int src = c2.y;
        const float4 ef = *(const float4*)(edge_feat + (size_t)e * 4);
        const _Float16* wr = w16 + (size_t)i * 128 + 4 * j;
        const half4v w0 = *(const half4v*)(wr);
        const half4v w1 = *(const half4v*)(wr + 32);
        const half4v w2 = *(const half4v*)(wr + 64);
        const half4v w3 = *(const half4v*)(wr + 96);
        const float* xr = node_feat + (size_t)src * 128;
        const float4 x0v = *(const float4*)(xr + 4 * j);
        const float4 xa  = *(const float4*)(xr + 32 + 12 * j);
        const float4 xb  = *(const float4*)(xr + 36 + 12 * j);
        const float4 xc  = *(const float4*)(xr + 40 + 12 * j);
        msg_accum(ef, w0, w1, w2, w3, x0v, xa, xb, xc, acc0, accm);
        ++i;
    }

    for (; i < end; i += 2) {
        // ---- issue ALL loads for both edges before any compute ----
        const int2 cA = csr2[i];
        const int2 cB = csr2[i + 1];
        const int eA = cA.x & 0xFFFFF, srcA = cA.y;
        const int eB = cB.x & 0xFFFFF, srcB = cB.y;

        const _Float16* wrA = w16 + (size_t)i * 128 + 4 * j;   // address independent of csr2!
        const _Float16* wrB = wrA + 128;
        const half4v wA0 = *(const half4v*)(wrA);
        const half4v wA1 = *(const half4v*)(wrA + 32);
        const half4v wA2 = *(const half4v*)(wrA + 64);
        const half4v wA3 = *(const half4v*)(wrA + 96);
        const half4v wB0 = *(const half4v*)(wrB);
        const half4v wB1 = *(const half4v*)(wrB + 32);
        const half4v wB2 = *(const half4v*)(wrB + 64);
        const half4v wB3 = *(const half4v*)(wrB + 96);

        const float4 efA = *(const float4*)(edge_feat + (size_t)eA * 4);
        const float4 efB = *(const float4*)(edge_feat + (size_t)eB * 4);

        const float* xrA = node_feat + (size_t)srcA * 128;
        const float* xrB = node_feat + (size_t)srcB * 128;
        const float4 xA0 = *(const float4*)(xrA + 4 * j);
        const float4 xAa = *(const float4*)(xrA + 32 + 12 * j);
        const float4 xAb = *(const float4*)(xrA + 36 + 12 * j);
        const float4 xAc = *(const float4*)(xrA + 40 + 12 * j);
        const float4 xB0 = *(const float4*)(xrB + 4 * j);
        const float4 xBa = *(const float4*)(xrB + 32 + 12 * j);
        const float4 xBb = *(const float4*)(xrB + 36 + 12 * j);
        const float4 xBc = *(const float4*)(xrB + 40 + 12 * j);

        msg_accum(efA, wA0, wA1, wA2, wA3, xA0, xAa, xAb, xAc, acc0, accm);
        msg_accum(efB, wB0, wB1, wB2, wB3, xB0, xBa, xBb, xBc, acc0, accm);
    }

    // ---- fused self-connection ----
    float s0[4]  = {0.f, 0.f, 0.f, 0.f};
    float s1[12] = {0.f};
    {
        const float* xr = xown + local * 129;
        #pragma unroll 4
        for (int u = 0; u < 32; ++u) {
            const float a0 = xr[u];
            const float ax = xr[32 + 3 * u], ay = xr[33 + 3 * u], az = xr[34 + 3 * u];
            const float* w0r = sw0 + u * 32 + 4 * j;
            const float* w1r = sw1 + u * 32 + 4 * j;
            #pragma unroll
            for (int k = 0; k < 4; ++k) {
                s0[k] += a0 * w0r[k];
                const float wv = w1r[k];
                s1[3 * k + 0] += ax * wv;
                s1[3 * k + 1] += ay * wv;
                s1[3 * k + 2] += az * wv;
            }
        }
    }

    // ---- writeout: out = agg + sc ----
    {
        float* op = out + (size_t)n * 128;
        float4 o0 = {acc0[0] + s0[0] * INV_SQRT_MUL,
                     acc0[1] + s0[1] * INV_SQRT_MUL,
                     acc0[2] + s0[2] * INV_SQRT_MUL,
                     acc0[3] + s0[3] * INV_SQRT_MUL};
        *(float4*)(op + 4 * j) = o0;

        float* mp = op + 32 + 12 * j;
        float4 m0 = {accm[0] + s1[0] * INV_SQRT_MUL,
                     accm[1] + s1[1] * INV_SQRT_MUL,
                     accm[2] + s1[2] * INV_SQRT_MUL,
                     accm[3] + s1[3] * INV_SQRT_MUL};
        float4 m1 = {accm[4] + s1[4] * INV_SQRT_MUL,
                     accm[5] + s1[5] * INV_SQRT_MUL,
                     accm[6] + s1[6] * INV_SQRT_MUL,
                     accm[7] + s1[7] * INV_SQRT_MUL};
        float4 m2 = {accm[8]  + s1[8]  * INV_SQRT_MUL,
                     accm[9]  + s1[9]  * INV_SQRT_MUL,
                     accm[10] + s1[10] * INV_SQRT_MUL,
                     accm[11] + s1[11] * INV_SQRT_MUL};
        *(float4*)(mp)     = m0;
        *(float4*)(mp + 4) = m1;
        *(float4*)(mp + 8) = m2;
    }
}

// ---------------- fused fallback (round-4 gather): used only if ws too small ----------------
__global__ __launch_bounds__(256, 2)
void gather_fused_kernel(const int* __restrict__ ei,
                         const int* __restrict__ row_ptr,
                         const int2* __restrict__ csr2,
                         const float* __restrict__ node_feat,
                         const float* __restrict__ edge_feat,
                         const float* __restrict__ edge_embed,
                         const _Float16* __restrict__ frags,
                         const float* __restrict__ B1,
                         const float* __restrict__ B2,
                         const float* __restrict__ B3,
                         float* __restrict__ out)
{
    __shared__ float    accum[NPB * ACC_STRIDE];
    __shared__ _Float16 H1b[4][16 * H1S];
    __shared__ _Float16 H2b[4][16 * H2S];
    __shared__ float    Wld[4][16 * WSTR];

    const int t  = threadIdx.x;
    const int w  = t >> 6;
    const int l  = t & 63;
    const int lg = l >> 4;
    const int lr = l & 15;

    const half8* f8 = (const half8*)frags;
    half8 w1f[4], w2f[2][2], w3f[8];
    #pragma unroll
    for (int i = 0; i < 4; ++i) w1f[i] = f8[i * 64 + l];
    #pragma unroll
    for (int kc = 0; kc < 2; ++kc)
        #pragma unroll
        for (int i = 0; i < 2; ++i) w2f[kc][i] = f8[256 + kc * 128 + i * 64 + l];
    #pragma unroll
    for (int i = 0; i < 8; ++i) w3f[i] = f8[512 + i * 64 + l];

    float b1r[4], b2r[2], b3r[8];
    #pragma unroll
    for (int i = 0; i < 4; ++i) b1r[i] = B1[i * 16 + lr];
    #pragma unroll
    for (int i = 0; i < 2; ++i) b2r[i] = B2[i * 16 + lr];
    #pragma unroll
    for (int i = 0; i < 8; ++i) b3r[i] = B3[i * 16 + lr];

    for (int i = t; i < NPB * ACC_STRIDE; i += 256) accum[i] = 0.0f;
    __syncthreads();

    const int node_base = blockIdx.x * NPB;
    const int nb_end    = (node_base + NPB < N_NODES) ? node_base + NPB : N_NODES;
    const int start     = row_ptr[node_base];
    const int end       = row_ptr[nb_end];
    const int cnt       = end - start;

    const floatx4 zero = {0.f, 0.f, 0.f, 0.f};
    _Float16* h1p = H1b[w];
    _Float16* h2p = H2b[w];
    float*    wp  = Wld[w];

    for (int tile = w; tile * 16 < cnt; tile += 4) {
        const int tb = start + tile * 16;
        const int iM  = tb + lr;
        const int iiM = (iM < end) ? iM : end - 1;
        const int eM  = csr2[iiM].x & 0xFFFFF;

        const int  q    = l & 3;
        const int  edg  = l >> 2;
        const int  iX   = tb + edg;
        const bool vX   = iX < end;
        const int  iiX  = vX ? iX : end - 1;
        const int2 enX  = csr2[iiX];
        const int  eX   = enX.x & 0xFFFFF;
        const int  locX = (enX.x >> 20) & (NPB - 1);
        const int  srcX = enX.y;

        float4 efX = {0.f, 0.f, 0.f, 0.f};
        if (vX) efX = *(const float4*)(edge_feat + (size_t)eX * 4);

        const float* xr = node_feat + (size_t)srcX * 128;
        float4 x0h[2], x1h[2][3];
        #pragma unroll
        for (int h = 0; h < 2; ++h) {
            x0h[h] = *(const float4*)(xr + h * 16 + q * 4);
            const float* xb = xr + 32 + 48 * h + 12 * q;
            x1h[h][0] = *(const float4*)(xb);
            x1h[h][1] = *(const float4*)(xb + 4);
            x1h[h][2] = *(const float4*)(xb + 8);
        }

        const float* ep = edge_embed + (size_t)eM * 32 + lg * 8;
        const float4 ea = *(const float4*)ep;
        const float4 eb = *(const float4*)(ep + 4);
        half8 a1;
        a1[0] = (_Float16)ea.x; a1[1] = (_Float16)ea.y;
        a1[2] = (_Float16)ea.z; a1[3] = (_Float16)ea.w;
        a1[4] = (_Float16)eb.x; a1[5] = (_Float16)eb.y;
        a1[6] = (_Float16)eb.z; a1[7] = (_Float16)eb.w;

        #pragma unroll
        for (int tt = 0; tt < 4; ++tt) {
            floatx4 c = __builtin_amdgcn_mfma_f32_16x16x32_f16(a1, w1f[tt], zero, 0, 0, 0);
            #pragma unroll
            for (int r = 0; r < 4; ++r) {
                const float v = silu_f(c[r] + b1r[tt]);
                h1p[(lg * 4 + r) * H1S + tt * 16 + lr] = (_Float16)v;
            }
        }
        const half8 a2_0 = *(const half8*)&h1p[lr * H1S +      lg * 8];
        const half8 a2_1 = *(const half8*)&h1p[lr * H1S + 32 + lg * 8];

        #pragma unroll
        for (int tt = 0; tt < 2; ++tt) {
            floatx4 c = __builtin_amdgcn_mfma_f32_16x16x32_f16(a2_0, w2f[0][tt], zero, 0, 0, 0);
            c = __builtin_amdgcn_mfma_f32_16x16x32_f16(a2_1, w2f[1][tt], c, 0, 0, 0);
            #pragma unroll
            for (int r = 0; r < 4; ++r) {
                const float v = silu_f(c[r] + b2r[tt]);
                h2p[(lg * 4 + r) * H2S + tt * 16 + lr] = (_Float16)v;
            }
        }
        const half8 a3 = *(const half8*)&h2p[lr * H2S + lg * 8];

        float* arow = accum + locX * ACC_STRIDE;
        #pragma unroll
        for (int h = 0; h < 2; ++h) {
            #pragma unroll
            for (int ttt = 0; ttt < 4; ++ttt) {
                const int tt = ttt * 2 + h;
                floatx4 c = __builtin_amdgcn_mfma_f32_16x16x32_f16(a3, w3f[tt], zero, 0, 0, 0);
                #pragma unroll
                for (int r = 0; r < 4; ++r)
                    wp[(lg * 4 + r) * WSTR + ttt * 16 + lr] = c[r] + b3r[tt];
            }

            const float4 w0v = *(const float4*)&wp[edg * WSTR +      q * 4];
            const float4 w1v = *(const float4*)&wp[edg * WSTR + 16 + q * 4];
            const float4 w2v = *(const float4*)&wp[edg * WSTR + 32 + q * 4];
            const float4 w3v = *(const float4*)&wp[edg * WSTR + 48 + q * 4];
            const float wa0[4] = {w0v.x, w0v.y, w0v.z, w0v.w};
            const float wa1[4] = {w1v.x, w1v.y, w1v.z, w1v.w};
            const float wa2[4] = {w2v.x, w2v.y, w2v.z, w2v.w};
            const float wa3[4] = {w3v.x, w3v.y, w3v.z, w3v.w};

            const float e0  = efX.x, e1x = efX.y, e1y = efX.z, e1z = efX.w;
            const float x0a[4] = {x0h[h].x, x0h[h].y, x0h[h].z, x0h[h].w};
            const float xx[12] = {x1h[h][0].x, x1h[h][0].y, x1h[h][0].z, x1h[h][0].w,
                                  x1h[h][1].x, x1h[h][1].y, x1h[h][1].z, x1h[h][1].w,
                                  x1h[h][2].x, x1h[h][2].y, x1h[h][2].z, x1h[h][2].w};
            #pragma unroll
            for (int k = 0; k < 4; ++k) {
                const int u = h * 16 + q * 4 + k;
                const float x1x = xx[3 * k], x1y = xx[3 * k + 1], x1z = xx[3 * k + 2];
                const float dot = x1x * e1x + x1y * e1y + x1z * e1z;
                const float o0  = S2 * wa0[k] * x0a[k] * e0 + S2_3 * wa3[k] * dot;
                const float a   = S2 * wa1[k] * x0a[k];
                const float b   = S2 * wa2[k] * e0;
                atomicAdd(arow + u,              o0);
                atomicAdd(arow + 32 + 3 * u + 0, a * e1x + b * x1x);
                atomicAdd(arow + 32 + 3 * u + 1, a * e1y + b * x1y);
                atomicAdd(arow + 32 + 3 * u + 2, a * e1z + b * x1z);
            }
        }
    }
    __syncthreads();

    for (int i = t; i < NPB * 32; i += 256) {
        const int local = i >> 5;
        const int f4    = i & 31;
        const int n     = node_base + local;
        if (n < N_NODES) {
            float* op = out + (size_t)n * 128 + f4 * 4;
            float4 o = *(float4*)op;
            const float* ar = accum + local * ACC_STRIDE + f4 * 4;
            o.x += ar[0]; o.y += ar[1]; o.z += ar[2]; o.w += ar[3];
            *(float4*)op = o;
        }
    }
}

extern "C" void kernel_launch(void* const* d_in, const int* in_sizes, int n_in,
                              void* d_out, int out_size, void* d_ws, size_t ws_size,
                              hipStream_t stream)
{
    const int*   ei         = (const int*)  d_in[0];
    const float* node_feat  = (const float*)d_in[1];
    const float* edge_feat  = (const float*)d_in[2];
    const float* edge_embed = (const float*)d_in[3];
    const float* fc_w1      = (const float*)d_in[4];
    const float* fc_b1      = (const float*)d_in[5];
    const float* fc_w2      = (const float*)d_in[6];
    const float* fc_b2      = (const float*)d_in[7];
    const float* fc_w3      = (const float*)d_in[8];
    const float* fc_b3      = (const float*)d_in[9];
    const float* sc_w0      = (const float*)d_in[10];
    const float* sc_w1      = (const float*)d_in[11];
    float* out = (float*)d_out;

    // workspace (int offsets): counts | row_ptr | cursor | bsum | boff | csr2 | frags | w16
    int*  ws      = (int*)d_ws;
    int*  counts  = ws;                                       // N_NODES
    int*  row_ptr = ws + 51200;                               // N_NODES+1
    int*  cursor  = ws + 102400;                              // N_NODES
    int*  bsum    = ws + 153600;                              // NB_SCAN
    int*  boff    = ws + 153856;                              // NB_SCAN
    int2* csr2    = (int2*)(ws + 154112);                     // 6.4 MB
    _Float16* frags = (_Float16*)((char*)d_ws + 7016448);     // 16 KB
    _Float16* w16   = (_Float16*)((char*)d_ws + 7032832);     // 204.8 MB
    const bool big_ws = (ws_size >= 7032832ULL + 204800000ULL);

    hipMemsetAsync(counts, 0, N_NODES * sizeof(int), stream);

    hist_kernel     <<<(N_EDGES / 4 + 255) / 256, 256, 0, stream>>>(ei, counts);
    bsum_kernel     <<<NB_SCAN, 256, 0, stream>>>(counts, cursor, bsum);
    scan_sums_kernel<<<2, 256, 0, stream>>>(bsum, boff, row_ptr,
                                            fc_w1, fc_w2, fc_w3, frags);
    apply_kernel    <<<NB_SCAN, 256, 0, stream>>>(boff, cursor, row_ptr);
    scatter_kernel  <<<N_EDGES / 256, 256, 0, stream>>>(ei, cursor, csr2);

    if (big_ws) {
        mlp_kernel<<<3125, 256, 0, stream>>>(csr2, edge_embed, frags, fc_b1, fc_b2, fc_b3, w16);
        gather2_kernel<<<N_NODES / NPB2, 128, 0, stream>>>(csr2, row_ptr,
                                                           node_feat, edge_feat, w16,
                                                           sc_w0, sc_w1, out);
    } else {
        sc_kernel<<<N_NODES / 8, 256, 0, stream>>>(node_feat, sc_w0, sc_w1, out);
        gather_fused_kernel<<<(N_NODES + NPB - 1) / NPB, 256, 0, stream>>>(
            ei, row_ptr, csr2, node_feat, edge_feat, edge_embed,
            frags, fc_b1, fc_b2, fc_b3, out);
    }
}